// Round 14
// baseline (429.153 us; speedup 1.0000x reference)
//
#include <hip/hip_runtime.h>
#include <hip/hip_fp16.h>

#define QN 900
#define CN 91
#define TOTN (QN * CN)   // 81900
#define KSEL 300
#define BN 4
#define OUTW 448
#define MASKPIX (OUTW * OUTW)        // 200704
#define OFFS_LABELS (BN * KSEL)      // 1200
#define OFFS_BOXES  (2 * BN * KSEL)  // 2400
#define OFFS_MASKS  (6 * BN * KSEL)  // 7200
#define MAXC 2048
#define BT 1024

#define APB 4                        // hist blocks per batch
#define AELEM (TOTN / APB)           // 20475 exact

typedef float floatx4 __attribute__((ext_vector_type(4)));

static __device__ __forceinline__ unsigned fkey(float f) {
    unsigned u = __float_as_uint(f);
    return (u & 0x80000000u) ? ~u : (u | 0x80000000u);
}

// ---- A: distributed top-byte histogram (16 blocks; leaves logits L2-hot) ----
__global__ __launch_bounds__(1024) void hist_part(
    const float* __restrict__ logits, unsigned* __restrict__ wsh)
{
    const int b = blockIdx.x >> 2, part = blockIdx.x & 3;
    const int tid = threadIdx.x;
    const float* lg = logits + (size_t)b * TOTN + (size_t)part * AELEM;

    __shared__ unsigned h[256 * 9];      // [bin][slot 0..7], pad 9
    for (int i = tid; i < 256 * 9; i += 1024) h[i] = 0;
    __syncthreads();
    const int sl = tid & 7;
    for (int i = tid; i < AELEM; i += 1024)
        atomicAdd(&h[(fkey(lg[i]) >> 24) * 9 + sl], 1u);
    __syncthreads();
    if (tid < 256) {
        unsigned s = 0;
#pragma unroll
        for (int k = 0; k < 8; ++k) s += h[tid * 9 + k];
        wsh[blockIdx.x * 256 + tid] = s;   // full overwrite every launch
    }
}

// ---- B: threshold + gather + exact-rank scatter (validated core) ----
__global__ __launch_bounds__(BT) void select_final(
    const float* __restrict__ logits, const float* __restrict__ boxes,
    const int* __restrict__ tsz, const unsigned* __restrict__ wsh,
    float* out, int* qsel)
{
    const int b = blockIdx.x;
    const int tid = threadIdx.x;
    const float* lg = logits + (size_t)b * TOTN;

    __shared__ unsigned hist[256];
    __shared__ int sh_bin, sh_want, sh_chunk;
    __shared__ unsigned sh_above, sh_cnt;
    __shared__ int cidx[MAXC];
    __shared__ unsigned ckey[MAXC];

    if (tid < 256) {
        unsigned s = 0;
#pragma unroll
        for (int p = 0; p < APB; ++p) s += wsh[(b * APB + p) * 256 + tid];
        hist[tid] = s;
    }
    __syncthreads();

    unsigned prefix = 0;
    int want = KSEL;
#pragma unroll
    for (int round = 0; round < 2; ++round) {
        const int shift = 24 - 8 * round;
        if (round > 0) {
            if (tid < 256) hist[tid] = 0;
            __syncthreads();
            for (int i = tid; i < TOTN; i += BT) {
                unsigned key = fkey(lg[i]);
                if ((key & 0xFF000000u) == prefix)
                    atomicAdd(&hist[(key >> 16) & 255u], 1u);
            }
            __syncthreads();
        }
        if (tid < 64) {
            unsigned p = hist[tid * 4] + hist[tid * 4 + 1]
                       + hist[tid * 4 + 2] + hist[tid * 4 + 3];
            unsigned suffix = p;
#pragma unroll
            for (int o = 1; o < 64; o <<= 1) {
                unsigned t = __shfl_down(suffix, o);
                if (tid + o < 64) suffix += t;
            }
            unsigned nxt = __shfl_down(suffix, 1);
            if (tid == 63) nxt = 0;
            bool flag = (suffix >= (unsigned)want) && (nxt < (unsigned)want);
            if (flag) { sh_chunk = tid; sh_above = nxt; }
        }
        __syncthreads();
        if (tid == 0) {
            int ch = sh_chunk;
            unsigned acc = sh_above;
            int j = 3;
            for (; j > 0; --j) {
                if (acc + hist[ch * 4 + j] >= (unsigned)want) break;
                acc += hist[ch * 4 + j];
            }
            sh_bin = ch * 4 + j;
            sh_want = want - (int)acc;
        }
        __syncthreads();
        prefix |= ((unsigned)sh_bin << shift);
        want = sh_want;
        __syncthreads();
    }
    const unsigned T16 = prefix >> 16;

    if (tid == 0) sh_cnt = 0;
    __syncthreads();
    for (int i = tid; i < TOTN; i += BT) {
        unsigned key = fkey(lg[i]);
        if ((key >> 16) >= T16) {
            unsigned p = atomicAdd(&sh_cnt, 1u);
            if (p < MAXC) { cidx[p] = i; ckey[p] = key; }
        }
    }
    __syncthreads();
    const int ncand = min((int)sh_cnt, MAXC);

    const float fh = (float)tsz[b * 2 + 0];
    const float fw = (float)tsz[b * 2 + 1];

    for (int c = tid; c < ncand; c += BT) {
        const unsigned kc = ckey[c];
        const int ic = cidx[c];
        int rank = 0;
        for (int s = 0; s < ncand; ++s) {
            unsigned ks = ckey[s];
            if (ks > kc || (ks == kc && cidx[s] < ic)) ++rank;
        }
        if (rank < KSEL) {
            float lf = lg[ic];
            float score = 1.0f / (1.0f + expf(-lf));
            int q = ic / CN;
            int label = ic - q * CN;

            out[b * KSEL + rank] = score;
            out[OFFS_LABELS + b * KSEL + rank] = (float)label;

            const float* bx = boxes + ((size_t)b * QN + q) * 4;
            float cx = bx[0], cy = bx[1], ww = bx[2], hh = bx[3];
            float* ob = out + OFFS_BOXES + ((size_t)(b * KSEL + rank)) * 4;
            ob[0] = (cx - 0.5f * ww) * fw;
            ob[1] = (cy - 0.5f * hh) * fh;
            ob[2] = (cx + 0.5f * ww) * fw;
            ob[3] = (cy + 0.5f * hh) * fh;

            qsel[b * KSEL + rank] = q;
        }
    }
}

// ---- mask resize core (R11/R13 structure), parameterized by effective block id ----
#define SPLIT 4
#define ROWSB (OUTW / SPLIT)   // 112 rows per block

static __device__ __forceinline__ void mask_body(
    const float* __restrict__ masks, const int* __restrict__ qsel,
    float* __restrict__ out, int ebid)
{
    const int mk = ebid >> 2;
    const int part = ebid & 3;
    const int b = mk / KSEL;
    const int q = qsel[mk];
    const float* __restrict__ src = masks + ((size_t)b * QN + q) * 784;

    const int j = threadIdx.x & 127;
    const int rhalf = threadIdx.x >> 7;
    if (j >= 112) return;

    const int qd = j & 3;
    const int i4 = j >> 2;
    const int c0 = i4 - 1 + (qd >> 1);
    const int c0c = c0 < 0 ? 0 : c0;
    const int c1c = (c0 + 1 > 27) ? 27 : c0 + 1;
    const float toff = 0.25f * (float)qd - ((qd >= 2) ? 1.0f : 0.0f);
    const float t0 = 0.53125f + toff, t1 = 0.59375f + toff,
                t2 = 0.65625f + toff, t3 = 0.71875f + toff;

    const int ystart = part * ROWSB + rhalf;
    float* optr = out + OFFS_MASKS + (size_t)mk * MASKPIX
                + (size_t)ystart * OUTW + j * 4;

    float sy = (float)ystart * 0.0625f - 0.46875f;
    int prev_iy = -1000;
    float m00 = 0.f, m01 = 0.f, d0 = 0.f, d1 = 0.f;

#pragma unroll 2
    for (int k = 0; k < ROWSB / 2; ++k) {
        float yf = floorf(sy);
        float ty = sy - yf;
        int iy = (int)yf;
        if (iy != prev_iy) {
            prev_iy = iy;
            int y0 = iy < 0 ? 0 : iy;
            int y1 = (iy + 1 > 27) ? 27 : iy + 1;
            float a0 = src[y0 * 28 + c0c];
            float a1 = src[y0 * 28 + c1c];
            float b0 = src[y1 * 28 + c0c];
            float b1 = src[y1 * 28 + c1c];
            m00 = a0; m01 = a1;
            d0 = b0 - a0; d1 = b1 - a1;
        }
        float v0 = fmaf(ty, d0, m00);
        float v1 = fmaf(ty, d1, m01);
        float dv = v1 - v0;
        floatx4 w;
        w.x = fmaf(t0, dv, v0);
        w.y = fmaf(t1, dv, v0);
        w.z = fmaf(t2, dv, v0);
        w.w = fmaf(t3, dv, v0);
        *reinterpret_cast<floatx4*>(optr) = w;
        optr += 2 * OUTW;
        sy += 0.125f;
    }
}

// plain mapping (R13 verbatim behavior)
__global__ __launch_bounds__(256) void mask_kernel(
    const float* __restrict__ masks, const int* __restrict__ qsel,
    float* __restrict__ out)
{
    mask_body(masks, qsel, out, blockIdx.x);
}

// XCD-contiguous mapping: round-robin bid%8 -> XCD; give each XCD one
// contiguous 600-region (=120 MB) span. 4800 % 8 == 0 -> bijective.
__global__ __launch_bounds__(256) void mask_kernel_swz(
    const float* __restrict__ masks, const int* __restrict__ qsel,
    float* __restrict__ out)
{
    const int ebid = (blockIdx.x & 7) * 600 + (blockIdx.x >> 3);
    mask_body(masks, qsel, out, ebid);
}

extern "C" void kernel_launch(void* const* d_in, const int* in_sizes, int n_in,
                              void* d_out, int out_size, void* d_ws, size_t ws_size,
                              hipStream_t stream) {
    const float* pred_logits = (const float*)d_in[0];
    const float* pred_boxes  = (const float*)d_in[1];
    const float* pred_masks  = (const float*)d_in[2];
    const int*   target_sz   = (const int*)d_in[3];
    float* out = (float*)d_out;
    int* qsel = (int*)d_ws;                                   // 4800 B
    unsigned* wsh = (unsigned*)((char*)d_ws + 5120);          // 16 KB

    hist_part<<<BN * APB, 1024, 0, stream>>>(pred_logits, wsh);
    select_final<<<BN, BT, 0, stream>>>(pred_logits, pred_boxes, target_sz,
                                        wsh, out, qsel);
    // measurement round: plain mask, then identical-output swizzled mask.
    // T14 - T13 = cost(mask_swz) exactly; output unchanged (same values twice).
    mask_kernel<<<BN * KSEL * SPLIT, 256, 0, stream>>>(pred_masks, qsel, out);
    mask_kernel_swz<<<BN * KSEL * SPLIT, 256, 0, stream>>>(pred_masks, qsel, out);
}

// Round 15
// 253.495 us; speedup vs baseline: 1.6929x; 1.6929x over previous
//
#include <hip/hip_runtime.h>
#include <hip/hip_fp16.h>

#define QN 900
#define CN 91
#define TOTN (QN * CN)   // 81900
#define KSEL 300
#define BN 4
#define OUTW 448
#define MASKPIX (OUTW * OUTW)        // 200704
#define OFFS_LABELS (BN * KSEL)      // 1200
#define OFFS_BOXES  (2 * BN * KSEL)  // 2400
#define OFFS_MASKS  (6 * BN * KSEL)  // 7200
#define MAXC 2048
#define BT 1024

#define APB 4                        // hist blocks per batch
#define AELEM (TOTN / APB)           // 20475 exact

typedef float floatx4 __attribute__((ext_vector_type(4)));

static __device__ __forceinline__ unsigned fkey(float f) {
    unsigned u = __float_as_uint(f);
    return (u & 0x80000000u) ? ~u : (u | 0x80000000u);
}

// ---- A: distributed top-byte histogram (16 blocks; leaves logits L2-hot) ----
__global__ __launch_bounds__(1024) void hist_part(
    const float* __restrict__ logits, unsigned* __restrict__ wsh)
{
    const int b = blockIdx.x >> 2, part = blockIdx.x & 3;
    const int tid = threadIdx.x;
    const float* lg = logits + (size_t)b * TOTN + (size_t)part * AELEM;

    __shared__ unsigned h[256 * 9];      // [bin][slot 0..7], pad 9
    for (int i = tid; i < 256 * 9; i += 1024) h[i] = 0;
    __syncthreads();
    const int sl = tid & 7;
    for (int i = tid; i < AELEM; i += 1024)
        atomicAdd(&h[(fkey(lg[i]) >> 24) * 9 + sl], 1u);
    __syncthreads();
    if (tid < 256) {
        unsigned s = 0;
#pragma unroll
        for (int k = 0; k < 8; ++k) s += h[tid * 9 + k];
        wsh[blockIdx.x * 256 + tid] = s;   // full overwrite every launch
    }
}

// ---- B: threshold + gather + exact-rank scatter (validated core) ----
__global__ __launch_bounds__(BT) void select_final(
    const float* __restrict__ logits, const float* __restrict__ boxes,
    const int* __restrict__ tsz, const unsigned* __restrict__ wsh,
    float* out, int* qsel)
{
    const int b = blockIdx.x;
    const int tid = threadIdx.x;
    const float* lg = logits + (size_t)b * TOTN;

    __shared__ unsigned hist[256];
    __shared__ int sh_bin, sh_want, sh_chunk;
    __shared__ unsigned sh_above, sh_cnt;
    __shared__ int cidx[MAXC];
    __shared__ unsigned ckey[MAXC];

    if (tid < 256) {
        unsigned s = 0;
#pragma unroll
        for (int p = 0; p < APB; ++p) s += wsh[(b * APB + p) * 256 + tid];
        hist[tid] = s;
    }
    __syncthreads();

    unsigned prefix = 0;
    int want = KSEL;
#pragma unroll
    for (int round = 0; round < 2; ++round) {
        const int shift = 24 - 8 * round;
        if (round > 0) {
            if (tid < 256) hist[tid] = 0;
            __syncthreads();
            for (int i = tid; i < TOTN; i += BT) {
                unsigned key = fkey(lg[i]);
                if ((key & 0xFF000000u) == prefix)
                    atomicAdd(&hist[(key >> 16) & 255u], 1u);
            }
            __syncthreads();
        }
        if (tid < 64) {
            unsigned p = hist[tid * 4] + hist[tid * 4 + 1]
                       + hist[tid * 4 + 2] + hist[tid * 4 + 3];
            unsigned suffix = p;
#pragma unroll
            for (int o = 1; o < 64; o <<= 1) {
                unsigned t = __shfl_down(suffix, o);
                if (tid + o < 64) suffix += t;
            }
            unsigned nxt = __shfl_down(suffix, 1);
            if (tid == 63) nxt = 0;
            bool flag = (suffix >= (unsigned)want) && (nxt < (unsigned)want);
            if (flag) { sh_chunk = tid; sh_above = nxt; }
        }
        __syncthreads();
        if (tid == 0) {
            int ch = sh_chunk;
            unsigned acc = sh_above;
            int j = 3;
            for (; j > 0; --j) {
                if (acc + hist[ch * 4 + j] >= (unsigned)want) break;
                acc += hist[ch * 4 + j];
            }
            sh_bin = ch * 4 + j;
            sh_want = want - (int)acc;
        }
        __syncthreads();
        prefix |= ((unsigned)sh_bin << shift);
        want = sh_want;
        __syncthreads();
    }
    const unsigned T16 = prefix >> 16;

    if (tid == 0) sh_cnt = 0;
    __syncthreads();
    for (int i = tid; i < TOTN; i += BT) {
        unsigned key = fkey(lg[i]);
        if ((key >> 16) >= T16) {
            unsigned p = atomicAdd(&sh_cnt, 1u);
            if (p < MAXC) { cidx[p] = i; ckey[p] = key; }
        }
    }
    __syncthreads();
    const int ncand = min((int)sh_cnt, MAXC);

    const float fh = (float)tsz[b * 2 + 0];
    const float fw = (float)tsz[b * 2 + 1];

    for (int c = tid; c < ncand; c += BT) {
        const unsigned kc = ckey[c];
        const int ic = cidx[c];
        int rank = 0;
        for (int s = 0; s < ncand; ++s) {
            unsigned ks = ckey[s];
            if (ks > kc || (ks == kc && cidx[s] < ic)) ++rank;
        }
        if (rank < KSEL) {
            float lf = lg[ic];
            float score = 1.0f / (1.0f + expf(-lf));
            int q = ic / CN;
            int label = ic - q * CN;

            out[b * KSEL + rank] = score;
            out[OFFS_LABELS + b * KSEL + rank] = (float)label;

            const float* bx = boxes + ((size_t)b * QN + q) * 4;
            float cx = bx[0], cy = bx[1], ww = bx[2], hh = bx[3];
            float* ob = out + OFFS_BOXES + ((size_t)(b * KSEL + rank)) * 4;
            ob[0] = (cx - 0.5f * ww) * fw;
            ob[1] = (cy - 0.5f * hh) * fh;
            ob[2] = (cx + 0.5f * ww) * fw;
            ob[3] = (cy + 0.5f * hh) * fh;

            qsel[b * KSEL + rank] = q;
        }
    }
}

// ---- mask resize core (R11/R13 structure), parameterized by effective block id ----
#define SPLIT 4
#define ROWSB (OUTW / SPLIT)   // 112 rows per block

static __device__ __forceinline__ void mask_body(
    const float* __restrict__ masks, const int* __restrict__ qsel,
    float* __restrict__ out, int ebid)
{
    const int mk = ebid >> 2;
    const int part = ebid & 3;
    const int b = mk / KSEL;
    const int q = qsel[mk];
    const float* __restrict__ src = masks + ((size_t)b * QN + q) * 784;

    const int j = threadIdx.x & 127;
    const int rhalf = threadIdx.x >> 7;
    if (j >= 112) return;

    const int qd = j & 3;
    const int i4 = j >> 2;
    const int c0 = i4 - 1 + (qd >> 1);
    const int c0c = c0 < 0 ? 0 : c0;
    const int c1c = (c0 + 1 > 27) ? 27 : c0 + 1;
    const float toff = 0.25f * (float)qd - ((qd >= 2) ? 1.0f : 0.0f);
    const float t0 = 0.53125f + toff, t1 = 0.59375f + toff,
                t2 = 0.65625f + toff, t3 = 0.71875f + toff;

    const int ystart = part * ROWSB + rhalf;
    float* optr = out + OFFS_MASKS + (size_t)mk * MASKPIX
                + (size_t)ystart * OUTW + j * 4;

    float sy = (float)ystart * 0.0625f - 0.46875f;
    int prev_iy = -1000;
    float m00 = 0.f, m01 = 0.f, d0 = 0.f, d1 = 0.f;

#pragma unroll 2
    for (int k = 0; k < ROWSB / 2; ++k) {
        float yf = floorf(sy);
        float ty = sy - yf;
        int iy = (int)yf;
        if (iy != prev_iy) {
            prev_iy = iy;
            int y0 = iy < 0 ? 0 : iy;
            int y1 = (iy + 1 > 27) ? 27 : iy + 1;
            float a0 = src[y0 * 28 + c0c];
            float a1 = src[y0 * 28 + c1c];
            float b0 = src[y1 * 28 + c0c];
            float b1 = src[y1 * 28 + c1c];
            m00 = a0; m01 = a1;
            d0 = b0 - a0; d1 = b1 - a1;
        }
        float v0 = fmaf(ty, d0, m00);
        float v1 = fmaf(ty, d1, m01);
        float dv = v1 - v0;
        floatx4 w;
        w.x = fmaf(t0, dv, v0);
        w.y = fmaf(t1, dv, v0);
        w.z = fmaf(t2, dv, v0);
        w.w = fmaf(t3, dv, v0);
        *reinterpret_cast<floatx4*>(optr) = w;
        optr += 2 * OUTW;
        sy += 0.125f;
    }
}

// XCD-contiguous mapping: round-robin bid%8 -> XCD; each XCD gets one
// contiguous 600-region (~120 MB) span. 4800 % 8 == 0 -> bijective.
__global__ __launch_bounds__(256) void mask_kernel_swz(
    const float* __restrict__ masks, const int* __restrict__ qsel,
    float* __restrict__ out)
{
    const int ebid = (blockIdx.x & 7) * 600 + (blockIdx.x >> 3);
    mask_body(masks, qsel, out, ebid);
}

extern "C" void kernel_launch(void* const* d_in, const int* in_sizes, int n_in,
                              void* d_out, int out_size, void* d_ws, size_t ws_size,
                              hipStream_t stream) {
    const float* pred_logits = (const float*)d_in[0];
    const float* pred_boxes  = (const float*)d_in[1];
    const float* pred_masks  = (const float*)d_in[2];
    const int*   target_sz   = (const int*)d_in[3];
    float* out = (float*)d_out;
    int* qsel = (int*)d_ws;                                   // 4800 B
    unsigned* wsh = (unsigned*)((char*)d_ws + 5120);          // 16 KB

    hist_part<<<BN * APB, 1024, 0, stream>>>(pred_logits, wsh);
    select_final<<<BN, BT, 0, stream>>>(pred_logits, pred_boxes, target_sz,
                                        wsh, out, qsel);
    mask_kernel_swz<<<BN * KSEL * SPLIT, 256, 0, stream>>>(pred_masks, qsel, out);
}